// Round 11
// baseline (532.128 us; speedup 1.0000x reference)
//
#include <hip/hip_runtime.h>
#include <hip/hip_cooperative_groups.h>

namespace cg = cooperative_groups;

// ResGCNBlock: out = LN(relu(scatter_add(norm * (xW^T+b)[row] -> col))) + x
// N=50000, D=128, E=800000, fp32.
// Round 21: cooperative-merge the 4 dependent mid kernels (partial, rowptrc,
//   fill, agg) into ONE kernel with grid.sync() phases. r20 accounting:
//   ~129us non-poison time vs ~65us of kernel work -> ~60us in dispatch
//   boundaries (drain+relaunch ~10us each). k_agg itself is at its
//   latency-concurrency floor (r13-r18 bracketed: ILP/TLP variants all
//   lost). Grid = co-resident capacity (occupancy query, cap 2048),
//   launch_bounds(256,8) => VGPR<=64 => 8 blocks/CU => agg at 32 waves/CU.
//   Fallback to the proven 4-kernel path if cooperative launch errors.
//   History: global atomics dead on gfx950 (r4/r7) -> LDS histograms (r8);
//   __shfl from inactive lanes UNDEFINED -> wave-uniform trips (r10);
//   NT streams (r11); 4-wide load groups (r12); pre8 u8 + srcs u16 (r20,
//   best=177.0).

#define D 128
#define CHSH 15                      // chunk = 32768 edges per hist block
#define CHUNK (1 << CHSH)
#define NWORD 12500                  // ceil(50000/4) packed-byte LDS words

typedef short bf16x8 __attribute__((ext_vector_type(8)));
typedef float f32x4 __attribute__((ext_vector_type(4)));

__device__ __forceinline__ unsigned short f2bf(float f) {
    unsigned u = __float_as_uint(f);
    return (unsigned short)((u + 0x7fffu + ((u >> 16) & 1u)) >> 16);
}
__device__ __forceinline__ float bf2f_lo(unsigned v) { return __uint_as_float(v << 16); }
__device__ __forceinline__ float bf2f_hi(unsigned v) { return __uint_as_float(v & 0xffff0000u); }

// ---------- merged (1024-thr): cnt-hist [0,K) + deg-hist [K,2K) + GEMM rest ----------
__global__ void __launch_bounds__(1024)
k_gemm_hist(const float* __restrict__ x, const float* __restrict__ W,
            const float* __restrict__ bias, unsigned short* __restrict__ hb,
            int nrows,
            const int* __restrict__ ei, int E, int n,
            unsigned char* __restrict__ degc, unsigned char* __restrict__ cntc,
            unsigned char* __restrict__ aux, int K) {
    __shared__ unsigned sm[NWORD];                 // 50 KB: hist OR W-frag staging
    int bid = blockIdx.x;
    if (bid < 2 * K) {
        unsigned* hist = sm;
        bool is_cnt = bid < K;
        int c = is_cnt ? bid : bid - K;
        const int* vs = is_cnt ? (ei + E) : ei;    // dest for cnt, source for deg
        for (int i = threadIdx.x; i < NWORD; i += 1024) hist[i] = 0u;
        __syncthreads();
        int e0 = c << CHSH;
        int e1 = e0 + CHUNK; if (e1 > E) e1 = E;
        if (is_cnt) {
            for (int e = e0 + threadIdx.x; e < e1; e += 1024) {
                int v = vs[e];
                unsigned sh = (v & 3) * 8;
                unsigned old = atomicAdd(&hist[v >> 2], 1u << sh);
                aux[e] = (unsigned char)(old >> sh);   // rank within (chunk, dest)
            }
        } else {
            for (int e = e0 + threadIdx.x; e < e1; e += 1024) {
                int v = vs[e];
                atomicAdd(&hist[v >> 2], 1u << ((v & 3) * 8));
            }
        }
        __syncthreads();
        unsigned* dst = (unsigned*)((is_cnt ? cntc : degc) + (size_t)c * n);
        for (int i = threadIdx.x; i < NWORD; i += 1024) dst[i] = hist[i];
    } else {
        // ---- GEMM role: 16 waves, 256 rows per block ----
        unsigned short* wf = (unsigned short*)sm;
        for (int s = threadIdx.x; s < D * D; s += 1024) {
            int j  = s & 7;
            int ln = (s >> 3) & 63;
            int g  = s >> 9;                       // nt*4 + kt
            int kt = g & 3, nt = g >> 2;
            int rw = nt * 16 + (ln & 15);
            int cl = kt * 32 + (ln >> 4) * 8 + j;
            wf[s] = f2bf(W[rw * D + cl]);
        }
        __syncthreads();

        int wid = threadIdx.x >> 6, lane = threadIdx.x & 63;
        int m0 = (bid - 2 * K) * 256 + wid * 16;
        if (m0 >= nrows) return;
        int lo16 = lane & 15, quad = lane >> 4;
        const float* arow = x + (size_t)(m0 + lo16) * D + quad * 8;
        bf16x8 a[4];
        #pragma unroll
        for (int kt = 0; kt < 4; kt++) {
            float4 p = *(const float4*)(arow + kt * 32);
            float4 q = *(const float4*)(arow + kt * 32 + 4);
            bf16x8 av;
            av[0] = (short)f2bf(p.x); av[1] = (short)f2bf(p.y);
            av[2] = (short)f2bf(p.z); av[3] = (short)f2bf(p.w);
            av[4] = (short)f2bf(q.x); av[5] = (short)f2bf(q.y);
            av[6] = (short)f2bf(q.z); av[7] = (short)f2bf(q.w);
            a[kt] = av;
        }
        const bf16x8* wfv = (const bf16x8*)sm;
        #pragma unroll
        for (int nt = 0; nt < 8; nt++) {
            int n0 = nt * 16;
            float bj = bias[n0 + lo16];
            f32x4 acc = {bj, bj, bj, bj};
            #pragma unroll
            for (int kt = 0; kt < 4; kt++) {
                bf16x8 b = wfv[(nt * 4 + kt) * 64 + lane];
                acc = __builtin_amdgcn_mfma_f32_16x16x32_bf16(a[kt], b, acc, 0, 0, 0);
            }
            #pragma unroll
            for (int r = 0; r < 4; r++) {
                int gr = m0 + quad * 4 + r;
                hb[(size_t)gr * D + n0 + lo16] = f2bf(acc[r]);
            }
        }
    }
}

// ---------- COOPERATIVE: partial -> rowptr/pre8 -> fill -> agg, grid.sync gaps ----------
__global__ void __launch_bounds__(256, 8)
k_coop(const float* __restrict__ x, const unsigned short* __restrict__ hb,
       const unsigned char* __restrict__ degc, const unsigned char* __restrict__ cntc,
       const unsigned char* __restrict__ aux, const int* __restrict__ ei,
       float* __restrict__ dis, unsigned* __restrict__ cnt,
       int* __restrict__ rowptr, unsigned char* __restrict__ pre8,
       unsigned* __restrict__ partial, unsigned short* __restrict__ srcs,
       const float* __restrict__ gamma, const float* __restrict__ beta,
       float* __restrict__ out, int n, int E, int K, int nb) {
    cg::grid_group grid = cg::this_grid();
    int bid = blockIdx.x, t = threadIdx.x;
    int NB = gridDim.x;
    __shared__ unsigned ps[256];
    __shared__ unsigned base_sh;

    // ---- PHASE 1: per-node deg/cnt reduce + per-block partial sums ----
    for (int b = bid; b < nb; b += NB) {
        int i = b * 256 + t;
        unsigned tot = 0;
        if (i < n) {
            unsigned d = 0;
            for (int c = 0; c < K; c++)
                d += __builtin_nontemporal_load(degc + (size_t)c * n + i);
            dis[i] = rsqrtf((float)d + 1.0f);      // +1 = self loop
            for (int c = 0; c < K; c++) tot += cntc[(size_t)c * n + i];
            cnt[i] = tot;
        }
        ps[t] = tot;
        __syncthreads();
        #pragma unroll
        for (int d = 128; d > 0; d >>= 1) {
            if (t < d) ps[t] += ps[t + d];
            __syncthreads();
        }
        if (t == 0) partial[b] = ps[0];
        __syncthreads();
    }
    grid.sync();

    // ---- PHASE 2: rowptr + per-chunk u8 prefix (redundant partial scan) ----
    for (int b = bid; b < nb; b += NB) {
        unsigned pv = (t < nb) ? partial[t] : 0u;
        ps[t] = pv;
        __syncthreads();
        #pragma unroll
        for (int d = 1; d < 256; d <<= 1) {
            unsigned u = (t >= d) ? ps[t - d] : 0u;
            __syncthreads();
            ps[t] += u;
            __syncthreads();
        }
        if (t == b) base_sh = ps[t] - pv;          // b < nb <= 256
        __syncthreads();
        unsigned bbase = base_sh;
        int i = b * 256 + t;
        unsigned v = (i < n) ? cnt[i] : 0u;
        ps[t] = v;
        __syncthreads();
        #pragma unroll
        for (int d = 1; d < 256; d <<= 1) {
            unsigned u = (t >= d) ? ps[t - d] : 0u;
            __syncthreads();
            ps[t] += u;
            __syncthreads();
        }
        if (i < n) {
            int base = (int)(bbase + ps[t] - v);
            rowptr[i] = base;
            unsigned run = 0;                      // run <= row degree << 255
            for (int c = 0; c < K; c++) {
                pre8[(size_t)c * n + i] = (unsigned char)run;
                run += cntc[(size_t)c * n + i];
            }
        }
        if (b == 0 && t == 0) rowptr[n] = E;
        __syncthreads();
    }
    grid.sync();

    // ---- PHASE 3: bucket fill (grid-stride over edges), srcs u16 ----
    for (int e = bid * 256 + t; e < E; e += NB * 256) {
        int r = __builtin_nontemporal_load(ei + e);
        int v = __builtin_nontemporal_load(ei + E + e);
        int c = e >> CHSH;
        int rank = __builtin_nontemporal_load(aux + e);
        int base = rowptr[v] + (int)pre8[(size_t)c * n + v];
        srcs[base + rank] = (unsigned short)r;
    }
    grid.sync();

    // ---- PHASE 4: gather-aggregate + self-loop + relu + LN + residual ----
    // r12's proven structure, grid-strided over row-groups of 4.
    int wid = t >> 6, lane = t & 63;
    int q = lane >> 4, tt = lane & 15;
    int nrg = (n + 3) >> 2;
    for (int rg = bid; rg < nrg; rg += NB) {
        int row = rg * 4 + wid;
        if (row >= n) continue;                    // wave-uniform guard
        float dc = dis[row];
        float acc[8];
        #pragma unroll
        for (int i = 0; i < 8; i++) acc[i] = 0.0f;
        if (q == 0) {                              // self-loop: dis^2 * h[row]
            uint4 u = ((const uint4*)(hb + (size_t)row * D))[tt];
            float sn = dc * dc;
            acc[0] = sn * bf2f_lo(u.x); acc[1] = sn * bf2f_hi(u.x);
            acc[2] = sn * bf2f_lo(u.y); acc[3] = sn * bf2f_hi(u.y);
            acc[4] = sn * bf2f_lo(u.z); acc[5] = sn * bf2f_hi(u.z);
            acc[6] = sn * bf2f_lo(u.w); acc[7] = sn * bf2f_hi(u.w);
        }
        int s0 = rowptr[row];
        int len = rowptr[row + 1] - s0;
        for (int base = 0; base < len; base += 64) {
            int idx = base + lane;
            int sv = (idx < len) ? (int)__builtin_nontemporal_load(srcs + s0 + idx) : 0;
            float dv = (idx < len) ? dis[sv] : 0.0f;   // pad: weight 0
            int m = len - base; if (m > 64) m = 64;
            int kmax = (m + 3) >> 2;               // 1..16, wave-uniform
            int gcount = (kmax + 3) >> 2;          // 1..4 groups of 4 edges/quad
            for (int gg = 0; gg < gcount; gg++) {  // wave-uniform trip count
                int jb = q + (gg << 4);            // jb+12 <= 63
                int r0 = __shfl(sv, jb, 64);
                int r1 = __shfl(sv, jb + 4, 64);
                int r2 = __shfl(sv, jb + 8, 64);
                int r3 = __shfl(sv, jb + 12, 64);
                float w0 = dc * __shfl(dv, jb, 64);
                float w1 = dc * __shfl(dv, jb + 4, 64);
                float w2 = dc * __shfl(dv, jb + 8, 64);
                float w3 = dc * __shfl(dv, jb + 12, 64);
                uint4 u0 = ((const uint4*)(hb + ((size_t)r0 << 7)))[tt];
                uint4 u1 = ((const uint4*)(hb + ((size_t)r1 << 7)))[tt];
                uint4 u2 = ((const uint4*)(hb + ((size_t)r2 << 7)))[tt];
                uint4 u3 = ((const uint4*)(hb + ((size_t)r3 << 7)))[tt];
                acc[0] += w0 * bf2f_lo(u0.x); acc[1] += w0 * bf2f_hi(u0.x);
                acc[2] += w0 * bf2f_lo(u0.y); acc[3] += w0 * bf2f_hi(u0.y);
                acc[4] += w0 * bf2f_lo(u0.z); acc[5] += w0 * bf2f_hi(u0.z);
                acc[6] += w0 * bf2f_lo(u0.w); acc[7] += w0 * bf2f_hi(u0.w);
                acc[0] += w1 * bf2f_lo(u1.x); acc[1] += w1 * bf2f_hi(u1.x);
                acc[2] += w1 * bf2f_lo(u1.y); acc[3] += w1 * bf2f_hi(u1.y);
                acc[4] += w1 * bf2f_lo(u1.z); acc[5] += w1 * bf2f_hi(u1.z);
                acc[6] += w1 * bf2f_lo(u1.w); acc[7] += w1 * bf2f_hi(u1.w);
                acc[0] += w2 * bf2f_lo(u2.x); acc[1] += w2 * bf2f_hi(u2.x);
                acc[2] += w2 * bf2f_lo(u2.y); acc[3] += w2 * bf2f_hi(u2.y);
                acc[4] += w2 * bf2f_lo(u2.z); acc[5] += w2 * bf2f_hi(u2.z);
                acc[6] += w2 * bf2f_lo(u2.w); acc[7] += w2 * bf2f_hi(u2.w);
                acc[0] += w3 * bf2f_lo(u3.x); acc[1] += w3 * bf2f_hi(u3.x);
                acc[2] += w3 * bf2f_lo(u3.y); acc[3] += w3 * bf2f_hi(u3.y);
                acc[4] += w3 * bf2f_lo(u3.z); acc[5] += w3 * bf2f_hi(u3.z);
                acc[6] += w3 * bf2f_lo(u3.w); acc[7] += w3 * bf2f_hi(u3.w);
            }
        }
        #pragma unroll
        for (int i = 0; i < 8; i++) {
            acc[i] += __shfl_xor(acc[i], 16, 64);
            acc[i] += __shfl_xor(acc[i], 32, 64);
            acc[i] = acc[i] > 0.0f ? acc[i] : 0.0f;
        }
        float s1r = 0.0f, s2r = 0.0f;
        #pragma unroll
        for (int i = 0; i < 8; i++) { s1r += acc[i]; s2r += acc[i] * acc[i]; }
        #pragma unroll
        for (int mm = 8; mm >= 1; mm >>= 1) {
            s1r += __shfl_xor(s1r, mm, 64);
            s2r += __shfl_xor(s2r, mm, 64);
        }
        float mean = s1r * (1.0f / 128.0f);
        float var  = s2r * (1.0f / 128.0f) - mean * mean;
        float rstd = rsqrtf(var + 1e-5f);
        if (q == 0) {                              // 16 lanes store the row
            const f32x4* gr = (const f32x4*)gamma;
            const f32x4* br = (const f32x4*)beta;
            const f32x4* xr = (const f32x4*)(x + (size_t)row * D);
            f32x4* orow = (f32x4*)(out + (size_t)row * D);
            #pragma unroll
            for (int hf = 0; hf < 2; hf++) {
                f32x4 g = gr[2 * tt + hf], b = br[2 * tt + hf];
                f32x4 xx = __builtin_nontemporal_load(xr + 2 * tt + hf);
                f32x4 o;
                o[0] = (acc[4 * hf + 0] - mean) * rstd * g[0] + b[0] + xx[0];
                o[1] = (acc[4 * hf + 1] - mean) * rstd * g[1] + b[1] + xx[1];
                o[2] = (acc[4 * hf + 2] - mean) * rstd * g[2] + b[2] + xx[2];
                o[3] = (acc[4 * hf + 3] - mean) * rstd * g[3] + b[3] + xx[3];
                __builtin_nontemporal_store(o, orow + 2 * tt + hf);
            }
        }
    }
}

// ================= fallback path (r20's proven separate kernels) =================
__global__ void k_partial(const unsigned char* __restrict__ degc,
                          const unsigned char* __restrict__ cntc,
                          float* __restrict__ dis, unsigned* __restrict__ cnt,
                          unsigned* __restrict__ partial, int n, int K) {
    __shared__ unsigned s[256];
    int t = threadIdx.x;
    int i = blockIdx.x * 256 + t;
    unsigned tot = 0;
    if (i < n) {
        unsigned d = 0;
        for (int c = 0; c < K; c++)
            d += __builtin_nontemporal_load(degc + (size_t)c * n + i);
        dis[i] = rsqrtf((float)d + 1.0f);
        for (int c = 0; c < K; c++) tot += cntc[(size_t)c * n + i];
        cnt[i] = tot;
    }
    s[t] = tot;
    __syncthreads();
    #pragma unroll
    for (int d = 128; d > 0; d >>= 1) {
        if (t < d) s[t] += s[t + d];
        __syncthreads();
    }
    if (t == 0) partial[blockIdx.x] = s[0];
}

__global__ void k_rowptrc(const unsigned* __restrict__ cnt, const unsigned char* __restrict__ cntc,
                          const unsigned* __restrict__ partial, int n, int E,
                          int* __restrict__ rowptr, unsigned char* __restrict__ pre8,
                          int K, int nb) {
    __shared__ unsigned ps[256];
    __shared__ unsigned base_sh;
    int t = threadIdx.x;
    unsigned pv = (t < nb) ? partial[t] : 0u;
    ps[t] = pv;
    __syncthreads();
    #pragma unroll
    for (int d = 1; d < 256; d <<= 1) {
        unsigned u = (t >= d) ? ps[t - d] : 0u;
        __syncthreads();
        ps[t] += u;
        __syncthreads();
    }
    if (t == blockIdx.x) base_sh = ps[t] - pv;
    __syncthreads();
    unsigned bbase = base_sh;
    int i = blockIdx.x * 256 + t;
    unsigned v = (i < n) ? cnt[i] : 0u;
    ps[t] = v;
    __syncthreads();
    #pragma unroll
    for (int d = 1; d < 256; d <<= 1) {
        unsigned u = (t >= d) ? ps[t - d] : 0u;
        __syncthreads();
        ps[t] += u;
        __syncthreads();
    }
    if (i < n) {
        int base = (int)(bbase + ps[t] - v);
        rowptr[i] = base;
        unsigned run = 0;
        for (int c = 0; c < K; c++) {
            pre8[(size_t)c * n + i] = (unsigned char)run;
            run += cntc[(size_t)c * n + i];
        }
    }
    if (blockIdx.x == 0 && t == 0) rowptr[n] = E;
}

__global__ void k_fill(const int* __restrict__ ei, int E, int n,
                       const int* __restrict__ rowptr, const unsigned char* __restrict__ pre8,
                       const unsigned char* __restrict__ aux,
                       unsigned short* __restrict__ srcs) {
    int e = blockIdx.x * 256 + threadIdx.x;
    if (e < E) {
        int r = __builtin_nontemporal_load(ei + e);
        int v = __builtin_nontemporal_load(ei + E + e);
        int c = e >> CHSH;
        int rank = __builtin_nontemporal_load(aux + e);
        int base = rowptr[v] + (int)pre8[(size_t)c * n + v];
        srcs[base + rank] = (unsigned short)r;
    }
}

__global__ void k_agg(const float* __restrict__ x, const unsigned short* __restrict__ hb,
                      const float* __restrict__ dis,
                      const int* __restrict__ rowptr, const unsigned short* __restrict__ srcs,
                      const float* __restrict__ gamma, const float* __restrict__ beta,
                      float* __restrict__ out, int n) {
    int wid = threadIdx.x >> 6, lane = threadIdx.x & 63;
    int row = blockIdx.x * 4 + wid;
    if (row >= n) return;
    int q = lane >> 4, t = lane & 15;
    float dc = dis[row];
    float acc[8];
    #pragma unroll
    for (int i = 0; i < 8; i++) acc[i] = 0.0f;
    if (q == 0) {
        uint4 u = ((const uint4*)(hb + (size_t)row * D))[t];
        float sn = dc * dc;
        acc[0] = sn * bf2f_lo(u.x); acc[1] = sn * bf2f_hi(u.x);
        acc[2] = sn * bf2f_lo(u.y); acc[3] = sn * bf2f_hi(u.y);
        acc[4] = sn * bf2f_lo(u.z); acc[5] = sn * bf2f_hi(u.z);
        acc[6] = sn * bf2f_lo(u.w); acc[7] = sn * bf2f_hi(u.w);
    }
    int s0 = rowptr[row];
    int len = rowptr[row + 1] - s0;
    for (int base = 0; base < len; base += 64) {
        int idx = base + lane;
        int sv = (idx < len) ? (int)__builtin_nontemporal_load(srcs + s0 + idx) : 0;
        float dv = (idx < len) ? dis[sv] : 0.0f;
        int m = len - base; if (m > 64) m = 64;
        int kmax = (m + 3) >> 2;
        int gcount = (kmax + 3) >> 2;
        for (int gg = 0; gg < gcount; gg++) {
            int jb = q + (gg << 4);
            int r0 = __shfl(sv, jb, 64);
            int r1 = __shfl(sv, jb + 4, 64);
            int r2 = __shfl(sv, jb + 8, 64);
            int r3 = __shfl(sv, jb + 12, 64);
            float w0 = dc * __shfl(dv, jb, 64);
            float w1 = dc * __shfl(dv, jb + 4, 64);
            float w2 = dc * __shfl(dv, jb + 8, 64);
            float w3 = dc * __shfl(dv, jb + 12, 64);
            uint4 u0 = ((const uint4*)(hb + ((size_t)r0 << 7)))[t];
            uint4 u1 = ((const uint4*)(hb + ((size_t)r1 << 7)))[t];
            uint4 u2 = ((const uint4*)(hb + ((size_t)r2 << 7)))[t];
            uint4 u3 = ((const uint4*)(hb + ((size_t)r3 << 7)))[t];
            acc[0] += w0 * bf2f_lo(u0.x); acc[1] += w0 * bf2f_hi(u0.x);
            acc[2] += w0 * bf2f_lo(u0.y); acc[3] += w0 * bf2f_hi(u0.y);
            acc[4] += w0 * bf2f_lo(u0.z); acc[5] += w0 * bf2f_hi(u0.z);
            acc[6] += w0 * bf2f_lo(u0.w); acc[7] += w0 * bf2f_hi(u0.w);
            acc[0] += w1 * bf2f_lo(u1.x); acc[1] += w1 * bf2f_hi(u1.x);
            acc[2] += w1 * bf2f_lo(u1.y); acc[3] += w1 * bf2f_hi(u1.y);
            acc[4] += w1 * bf2f_lo(u1.z); acc[5] += w1 * bf2f_hi(u1.z);
            acc[6] += w1 * bf2f_lo(u1.w); acc[7] += w1 * bf2f_hi(u1.w);
            acc[0] += w2 * bf2f_lo(u2.x); acc[1] += w2 * bf2f_hi(u2.x);
            acc[2] += w2 * bf2f_lo(u2.y); acc[3] += w2 * bf2f_hi(u2.y);
            acc[4] += w2 * bf2f_lo(u2.z); acc[5] += w2 * bf2f_hi(u2.z);
            acc[6] += w2 * bf2f_lo(u2.w); acc[7] += w2 * bf2f_hi(u2.w);
            acc[0] += w3 * bf2f_lo(u3.x); acc[1] += w3 * bf2f_hi(u3.x);
            acc[2] += w3 * bf2f_lo(u3.y); acc[3] += w3 * bf2f_hi(u3.y);
            acc[4] += w3 * bf2f_lo(u3.z); acc[5] += w3 * bf2f_hi(u3.z);
            acc[6] += w3 * bf2f_lo(u3.w); acc[7] += w3 * bf2f_hi(u3.w);
        }
    }
    #pragma unroll
    for (int i = 0; i < 8; i++) {
        acc[i] += __shfl_xor(acc[i], 16, 64);
        acc[i] += __shfl_xor(acc[i], 32, 64);
        acc[i] = acc[i] > 0.0f ? acc[i] : 0.0f;
    }
    float s1r = 0.0f, s2r = 0.0f;
    #pragma unroll
    for (int i = 0; i < 8; i++) { s1r += acc[i]; s2r += acc[i] * acc[i]; }
    #pragma unroll
    for (int mm = 8; mm >= 1; mm >>= 1) {
        s1r += __shfl_xor(s1r, mm, 64);
        s2r += __shfl_xor(s2r, mm, 64);
    }
    float mean = s1r * (1.0f / 128.0f);
    float var  = s2r * (1.0f / 128.0f) - mean * mean;
    float rstd = rsqrtf(var + 1e-5f);
    if (q == 0) {
        const f32x4* gr = (const f32x4*)gamma;
        const f32x4* br = (const f32x4*)beta;
        const f32x4* xr = (const f32x4*)(x + (size_t)row * D);
        f32x4* orow = (f32x4*)(out + (size_t)row * D);
        #pragma unroll
        for (int hf = 0; hf < 2; hf++) {
            f32x4 g = gr[2 * t + hf], b = br[2 * t + hf];
            f32x4 xx = __builtin_nontemporal_load(xr + 2 * t + hf);
            f32x4 o;
            o[0] = (acc[4 * hf + 0] - mean) * rstd * g[0] + b[0] + xx[0];
            o[1] = (acc[4 * hf + 1] - mean) * rstd * g[1] + b[1] + xx[1];
            o[2] = (acc[4 * hf + 2] - mean) * rstd * g[2] + b[2] + xx[2];
            o[3] = (acc[4 * hf + 3] - mean) * rstd * g[3] + b[3] + xx[3];
            __builtin_nontemporal_store(o, orow + 2 * t + hf);
        }
    }
}

extern "C" void kernel_launch(void* const* d_in, const int* in_sizes, int n_in,
                              void* d_out, int out_size, void* d_ws, size_t ws_size,
                              hipStream_t stream) {
    const float* x     = (const float*)d_in[0];
    const int*   ei    = (const int*)d_in[1];   // [2, E]
    const float* W     = (const float*)d_in[2];
    const float* bias  = (const float*)d_in[3];
    const float* gamma = (const float*)d_in[4];
    const float* beta  = (const float*)d_in[5];
    int N = in_sizes[0] / D;
    int E = in_sizes[1] / 2;
    int nb  = (N + 255) / 256;                   // 196 scan blocks (<=256)
    int nbE = (E + 255) / 256;                   // 3125
    int K   = (E + CHUNK - 1) >> CHSH;           // 25 chunks / copies
    int gemm_blocks = (N + 255) / 256;           // 196 (256 rows per 1024-thr block)

    char* ws = (char*)d_ws;
    size_t off = 0;
    unsigned short* hb  = (unsigned short*)(ws + off); off += (size_t)N * D * 2;       // 12.8 MB
    unsigned char* degc = (unsigned char*)(ws + off);  off += (size_t)K * N;           // 1.25 MB
    unsigned char* cntc = (unsigned char*)(ws + off);  off += (size_t)K * N;           // 1.25 MB
    float*    dis       = (float*)(ws + off);          off += (size_t)N * 4;
    unsigned* cnt       = (unsigned*)(ws + off);       off += (size_t)N * 4;
    int*      rowptr    = (int*)(ws + off);            off += (size_t)(N + 1) * 4;
    unsigned char* pre8 = (unsigned char*)(ws + off);  off += (size_t)K * N;           // 1.25 MB
    unsigned* partial   = (unsigned*)(ws + off);       off += 256 * 4;
    unsigned char* aux  = (unsigned char*)(ws + off);  off += (size_t)E;               // 0.8 MB
    off = (off + 1) & ~(size_t)1;
    unsigned short* srcs = (unsigned short*)(ws + off); off += (size_t)E * 2;          // 1.6 MB
    float*    out       = (float*)d_out;

    // co-resident grid size for the cooperative kernel (cached host queries)
    static int NB_cached = 0;
    if (NB_cached == 0) {
        int bpc = 0;
        if (hipOccupancyMaxActiveBlocksPerMultiprocessor(&bpc, k_coop, 256, 0) != hipSuccess || bpc < 1)
            bpc = 2;
        int dev = 0;
        hipGetDevice(&dev);
        hipDeviceProp_t prop;
        int ncu = 256;
        if (hipGetDeviceProperties(&prop, dev) == hipSuccess && prop.multiProcessorCount > 0)
            ncu = prop.multiProcessorCount;
        long long nbl = (long long)bpc * ncu;
        if (nbl > 2048) nbl = 2048;
        if (nbl < 64) nbl = 64;
        NB_cached = (int)nbl;
    }
    int NB = NB_cached;

    k_gemm_hist<<<2 * K + gemm_blocks, 1024, 0, stream>>>(x, W, bias, hb, N,
                                                          ei, E, N, degc, cntc, aux, K);

    void* args[] = { (void*)&x, (void*)&hb, (void*)&degc, (void*)&cntc, (void*)&aux,
                     (void*)&ei, (void*)&dis, (void*)&cnt, (void*)&rowptr, (void*)&pre8,
                     (void*)&partial, (void*)&srcs, (void*)&gamma, (void*)&beta,
                     (void*)&out, (void*)&N, (void*)&E, (void*)&K, (void*)&nb };
    hipError_t cerr = hipLaunchCooperativeKernel((const void*)k_coop, dim3(NB), dim3(256),
                                                 args, 0, stream);
    if (cerr != hipSuccess) {
        // fallback: proven r20 4-kernel path
        k_partial<<<nb, 256, 0, stream>>>(degc, cntc, dis, cnt, partial, N, K);
        k_rowptrc<<<nb, 256, 0, stream>>>(cnt, cntc, partial, N, E, rowptr, pre8, K, nb);
        k_fill<<<nbE, 256, 0, stream>>>(ei, E, N, rowptr, pre8, aux, srcs);
        k_agg<<<(N + 3) / 4, 256, 0, stream>>>(x, hb, dis, rowptr, srcs, gamma, beta, out, N);
    }
}

// Round 12
// 173.398 us; speedup vs baseline: 3.0688x; 3.0688x over previous
//
#include <hip/hip_runtime.h>

// ResGCNBlock: out = LN(relu(scatter_add(norm * (xW^T+b)[row] -> col))) + x
// N=50000, D=128, E=800000, fp32.
// Round 22: r20 base (best=177.0) + single-pass scan. r21's cooperative
//   grid.sync cost ~100us+/sync on gfx950 (k_coop 662us, VALU 3.7%) ->
//   cooperative merge abandoned. Instead: k_partial+k_rowptrc merged into
//   k_scan via decoupled lookback (196 blocks co-resident << capacity, no
//   deadlock): one cntc pass computes pre8+tot, block aggregate published
//   with READY bit (device-scope atomics, partial[] pre-zeroed inside
//   k_gemm_hist), predecessors' aggregates summed for the exclusive base.
//   Kills one launch boundary + cnt[] round-trip + one cntc pass.
//   History: global atomics dead on gfx950 (r4/r7) -> LDS histograms (r8);
//   __shfl from inactive lanes UNDEFINED -> wave-uniform trips (r10);
//   NT streams (r11); 4-wide load groups (r12); k_agg ILP/TLP variants all
//   regressed (r13-r18) -> r12 structure is the gather floor; pre8 u8 +
//   srcs u16 (r20); cooperative merge (r21, 3x worse).

#define D 128
#define CHSH 15                      // chunk = 32768 edges per hist block
#define CHUNK (1 << CHSH)
#define NWORD 12500                  // ceil(50000/4) packed-byte LDS words

typedef short bf16x8 __attribute__((ext_vector_type(8)));
typedef float f32x4 __attribute__((ext_vector_type(4)));

__device__ __forceinline__ unsigned short f2bf(float f) {
    unsigned u = __float_as_uint(f);
    return (unsigned short)((u + 0x7fffu + ((u >> 16) & 1u)) >> 16);
}
__device__ __forceinline__ float bf2f_lo(unsigned v) { return __uint_as_float(v << 16); }
__device__ __forceinline__ float bf2f_hi(unsigned v) { return __uint_as_float(v & 0xffff0000u); }

// ---------- merged (1024-thr): cnt-hist [0,K) + deg-hist [K,2K) + GEMM rest ----------
// block 0 additionally zeroes partial[] (consumed by k_scan, next dispatch).
__global__ void __launch_bounds__(1024)
k_gemm_hist(const float* __restrict__ x, const float* __restrict__ W,
            const float* __restrict__ bias, unsigned short* __restrict__ hb,
            int nrows,
            const int* __restrict__ ei, int E, int n,
            unsigned char* __restrict__ degc, unsigned char* __restrict__ cntc,
            unsigned char* __restrict__ aux, unsigned* __restrict__ partial, int K) {
    __shared__ unsigned sm[NWORD];                 // 50 KB: hist OR W-frag staging
    int bid = blockIdx.x;
    if (bid < 2 * K) {
        if (bid == 0 && threadIdx.x < 256) partial[threadIdx.x] = 0u;  // lookback flags
        unsigned* hist = sm;
        bool is_cnt = bid < K;
        int c = is_cnt ? bid : bid - K;
        const int* vs = is_cnt ? (ei + E) : ei;    // dest for cnt, source for deg
        for (int i = threadIdx.x; i < NWORD; i += 1024) hist[i] = 0u;
        __syncthreads();
        int e0 = c << CHSH;
        int e1 = e0 + CHUNK; if (e1 > E) e1 = E;
        if (is_cnt) {
            for (int e = e0 + threadIdx.x; e < e1; e += 1024) {
                int v = vs[e];
                unsigned sh = (v & 3) * 8;
                unsigned old = atomicAdd(&hist[v >> 2], 1u << sh);
                aux[e] = (unsigned char)(old >> sh);   // rank within (chunk, dest)
            }
        } else {
            for (int e = e0 + threadIdx.x; e < e1; e += 1024) {
                int v = vs[e];
                atomicAdd(&hist[v >> 2], 1u << ((v & 3) * 8));
            }
        }
        __syncthreads();
        unsigned* dst = (unsigned*)((is_cnt ? cntc : degc) + (size_t)c * n);
        for (int i = threadIdx.x; i < NWORD; i += 1024) dst[i] = hist[i];
    } else {
        // ---- GEMM role: 16 waves, 256 rows per block ----
        unsigned short* wf = (unsigned short*)sm;
        for (int s = threadIdx.x; s < D * D; s += 1024) {
            int j  = s & 7;
            int ln = (s >> 3) & 63;
            int g  = s >> 9;                       // nt*4 + kt
            int kt = g & 3, nt = g >> 2;
            int rw = nt * 16 + (ln & 15);
            int cl = kt * 32 + (ln >> 4) * 8 + j;
            wf[s] = f2bf(W[rw * D + cl]);
        }
        __syncthreads();

        int wid = threadIdx.x >> 6, lane = threadIdx.x & 63;
        int m0 = (bid - 2 * K) * 256 + wid * 16;
        if (m0 >= nrows) return;
        int lo16 = lane & 15, quad = lane >> 4;
        const float* arow = x + (size_t)(m0 + lo16) * D + quad * 8;
        bf16x8 a[4];
        #pragma unroll
        for (int kt = 0; kt < 4; kt++) {
            float4 p = *(const float4*)(arow + kt * 32);
            float4 q = *(const float4*)(arow + kt * 32 + 4);
            bf16x8 av;
            av[0] = (short)f2bf(p.x); av[1] = (short)f2bf(p.y);
            av[2] = (short)f2bf(p.z); av[3] = (short)f2bf(p.w);
            av[4] = (short)f2bf(q.x); av[5] = (short)f2bf(q.y);
            av[6] = (short)f2bf(q.z); av[7] = (short)f2bf(q.w);
            a[kt] = av;
        }
        const bf16x8* wfv = (const bf16x8*)sm;
        #pragma unroll
        for (int nt = 0; nt < 8; nt++) {
            int n0 = nt * 16;
            float bj = bias[n0 + lo16];
            f32x4 acc = {bj, bj, bj, bj};
            #pragma unroll
            for (int kt = 0; kt < 4; kt++) {
                bf16x8 b = wfv[(nt * 4 + kt) * 64 + lane];
                acc = __builtin_amdgcn_mfma_f32_16x16x32_bf16(a[kt], b, acc, 0, 0, 0);
            }
            #pragma unroll
            for (int r = 0; r < 4; r++) {
                int gr = m0 + quad * 4 + r;
                hb[(size_t)gr * D + n0 + lo16] = f2bf(acc[r]);
            }
        }
    }
}

// ---------- single-pass scan: dis + pre8 + rowptr via decoupled lookback ----------
// 196 blocks (all co-resident: no deadlock). Block publishes its aggregate
// with READY (bit31); waits for predecessors' aggregates; sums -> base.
__global__ void k_scan(const unsigned char* __restrict__ degc,
                       const unsigned char* __restrict__ cntc,
                       float* __restrict__ dis, int* __restrict__ rowptr,
                       unsigned char* __restrict__ pre8,
                       unsigned* __restrict__ partial, int n, int E, int K) {
    __shared__ unsigned ps[256];
    __shared__ unsigned bb_sh;
    int t = threadIdx.x, bid = blockIdx.x;
    int i = bid * 256 + t;
    unsigned tot = 0;
    if (i < n) {
        unsigned d = 0;
        for (int c = 0; c < K; c++)
            d += __builtin_nontemporal_load(degc + (size_t)c * n + i);  // read-once
        dis[i] = rsqrtf((float)d + 1.0f);          // +1 = self loop
        unsigned run = 0;                          // run <= row degree << 255
        for (int c = 0; c < K; c++) {
            pre8[(size_t)c * n + i] = (unsigned char)run;
            run += cntc[(size_t)c * n + i];        // single cntc pass (was 2)
        }
        tot = run;
    }
    // inclusive block scan of tot
    ps[t] = tot;
    __syncthreads();
    #pragma unroll
    for (int d = 1; d < 256; d <<= 1) {
        unsigned u = (t >= d) ? ps[t - d] : 0u;
        __syncthreads();
        ps[t] += u;
        __syncthreads();
    }
    unsigned incl = ps[t];
    unsigned agg  = ps[255];                       // block aggregate
    // wave 0: publish aggregate, then lookback-sum all predecessors
    if (t < 64) {
        if (t == 0) atomicExch(&partial[bid], agg | 0x80000000u);
        unsigned sum = 0;
        for (int j0 = 0; j0 < bid; j0 += 64) {
            int j = j0 + t;
            if (j < bid) {
                unsigned v;
                do { v = atomicAdd(&partial[j], 0u); } while (!(v & 0x80000000u));
                sum += v & 0x7fffffffu;
            }
        }
        #pragma unroll
        for (int mm = 32; mm >= 1; mm >>= 1) sum += __shfl_xor(sum, mm, 64);
        if (t == 0) bb_sh = sum;
    }
    __syncthreads();
    unsigned bbase = bb_sh;
    if (i < n) rowptr[i] = (int)(bbase + incl - tot);
    if (bid == 0 && t == 0) rowptr[n] = E;
}

// ---------- atomic-free bucket fill using (copy = e>>CHSH, rank = aux[e]) ----------
// srcs stored as u16 (N = 50000 < 65536).
__global__ void k_fill(const int* __restrict__ ei, int E, int n,
                       const int* __restrict__ rowptr, const unsigned char* __restrict__ pre8,
                       const unsigned char* __restrict__ aux,
                       unsigned short* __restrict__ srcs) {
    int e = blockIdx.x * 256 + threadIdx.x;
    if (e < E) {
        int r = __builtin_nontemporal_load(ei + e);          // read-once
        int v = __builtin_nontemporal_load(ei + E + e);      // read-once
        int c = e >> CHSH;
        int rank = __builtin_nontemporal_load(aux + e);      // read-once
        int base = rowptr[v] + (int)pre8[(size_t)c * n + v]; // hot 200KB + 1.25MB
        srcs[base + rank] = (unsigned short)r;               // 2B scatter
    }
}

// ---------- fused gather-aggregate + self-loop + relu + LN + residual ----------
// r12's proven structure: one wave per dest row; quad q (16 lanes) handles
// edges j==q (mod 4); lane t owns cols 8t..8t+7 (16B uint4 of bf16 per
// edge). 4-wide load groups: issue 4 independent gathers per quad, then
// consume. Group count wave-uniform; all shuffles full-wave (inactive-lane
// shuffle UNDEFINED on gfx950); pad lanes carry sv=0/dv=0 and self-mask.
__global__ void k_agg(const float* __restrict__ x, const unsigned short* __restrict__ hb,
                      const float* __restrict__ dis,
                      const int* __restrict__ rowptr, const unsigned short* __restrict__ srcs,
                      const float* __restrict__ gamma, const float* __restrict__ beta,
                      float* __restrict__ out, int n) {
    int wid = threadIdx.x >> 6, lane = threadIdx.x & 63;
    int row = blockIdx.x * 4 + wid;
    if (row >= n) return;
    int q = lane >> 4, t = lane & 15;
    float dc = dis[row];
    float acc[8];
    #pragma unroll
    for (int i = 0; i < 8; i++) acc[i] = 0.0f;
    if (q == 0) {                                     // self-loop: dis^2 * h[row]
        uint4 u = ((const uint4*)(hb + (size_t)row * D))[t];
        float sn = dc * dc;
        acc[0] = sn * bf2f_lo(u.x); acc[1] = sn * bf2f_hi(u.x);
        acc[2] = sn * bf2f_lo(u.y); acc[3] = sn * bf2f_hi(u.y);
        acc[4] = sn * bf2f_lo(u.z); acc[5] = sn * bf2f_hi(u.z);
        acc[6] = sn * bf2f_lo(u.w); acc[7] = sn * bf2f_hi(u.w);
    }
    int s0 = rowptr[row];
    int len = rowptr[row + 1] - s0;
    for (int base = 0; base < len; base += 64) {
        int idx = base + lane;
        int sv = (idx < len) ? (int)__builtin_nontemporal_load(srcs + s0 + idx) : 0;
        float dv = (idx < len) ? dis[sv] : 0.0f;      // pad: weight 0 (self-masks)
        int m = len - base; if (m > 64) m = 64;
        int kmax = (m + 3) >> 2;                      // 1..16, wave-uniform
        int gcount = (kmax + 3) >> 2;                 // 1..4 groups of 4 edges/quad
        for (int gg = 0; gg < gcount; gg++) {         // wave-uniform trip count
            int jb = q + (gg << 4);                   // jb+12 <= 63
            int r0 = __shfl(sv, jb, 64);
            int r1 = __shfl(sv, jb + 4, 64);
            int r2 = __shfl(sv, jb + 8, 64);
            int r3 = __shfl(sv, jb + 12, 64);
            float w0 = dc * __shfl(dv, jb, 64);       // 0 for stages >= m
            float w1 = dc * __shfl(dv, jb + 4, 64);
            float w2 = dc * __shfl(dv, jb + 8, 64);
            float w3 = dc * __shfl(dv, jb + 12, 64);
            // 4 independent gathers in flight before any consume
            uint4 u0 = ((const uint4*)(hb + ((size_t)r0 << 7)))[t];
            uint4 u1 = ((const uint4*)(hb + ((size_t)r1 << 7)))[t];
            uint4 u2 = ((const uint4*)(hb + ((size_t)r2 << 7)))[t];
            uint4 u3 = ((const uint4*)(hb + ((size_t)r3 << 7)))[t];
            acc[0] += w0 * bf2f_lo(u0.x); acc[1] += w0 * bf2f_hi(u0.x);
            acc[2] += w0 * bf2f_lo(u0.y); acc[3] += w0 * bf2f_hi(u0.y);
            acc[4] += w0 * bf2f_lo(u0.z); acc[5] += w0 * bf2f_hi(u0.z);
            acc[6] += w0 * bf2f_lo(u0.w); acc[7] += w0 * bf2f_hi(u0.w);
            acc[0] += w1 * bf2f_lo(u1.x); acc[1] += w1 * bf2f_hi(u1.x);
            acc[2] += w1 * bf2f_lo(u1.y); acc[3] += w1 * bf2f_hi(u1.y);
            acc[4] += w1 * bf2f_lo(u1.z); acc[5] += w1 * bf2f_hi(u1.z);
            acc[6] += w1 * bf2f_lo(u1.w); acc[7] += w1 * bf2f_hi(u1.w);
            acc[0] += w2 * bf2f_lo(u2.x); acc[1] += w2 * bf2f_hi(u2.x);
            acc[2] += w2 * bf2f_lo(u2.y); acc[3] += w2 * bf2f_hi(u2.y);
            acc[4] += w2 * bf2f_lo(u2.z); acc[5] += w2 * bf2f_hi(u2.z);
            acc[6] += w2 * bf2f_lo(u2.w); acc[7] += w2 * bf2f_hi(u2.w);
            acc[0] += w3 * bf2f_lo(u3.x); acc[1] += w3 * bf2f_hi(u3.x);
            acc[2] += w3 * bf2f_lo(u3.y); acc[3] += w3 * bf2f_hi(u3.y);
            acc[4] += w3 * bf2f_lo(u3.z); acc[5] += w3 * bf2f_hi(u3.z);
            acc[6] += w3 * bf2f_lo(u3.w); acc[7] += w3 * bf2f_hi(u3.w);
        }
    }
    // combine the 4 quads' partials (lanes t, t+16, t+32, t+48), then relu
    #pragma unroll
    for (int i = 0; i < 8; i++) {
        acc[i] += __shfl_xor(acc[i], 16, 64);
        acc[i] += __shfl_xor(acc[i], 32, 64);
        acc[i] = acc[i] > 0.0f ? acc[i] : 0.0f;
    }
    // LN over 128 cols: per-lane partial over its 8 cols, reduce across t
    float s1r = 0.0f, s2r = 0.0f;
    #pragma unroll
    for (int i = 0; i < 8; i++) { s1r += acc[i]; s2r += acc[i] * acc[i]; }
    #pragma unroll
    for (int mm = 8; mm >= 1; mm >>= 1) {
        s1r += __shfl_xor(s1r, mm, 64);
        s2r += __shfl_xor(s2r, mm, 64);
    }
    float mean = s1r * (1.0f / 128.0f);
    float var  = s2r * (1.0f / 128.0f) - mean * mean;  // population var (jnp.var)
    float rstd = rsqrtf(var + 1e-5f);
    if (q == 0) {                                      // 16 lanes store the row
        const f32x4* gr = (const f32x4*)gamma;
        const f32x4* br = (const f32x4*)beta;
        const f32x4* xr = (const f32x4*)(x + (size_t)row * D);
        f32x4* orow = (f32x4*)(out + (size_t)row * D);
        #pragma unroll
        for (int hf = 0; hf < 2; hf++) {
            f32x4 g = gr[2 * t + hf], b = br[2 * t + hf];
            f32x4 xx = __builtin_nontemporal_load(xr + 2 * t + hf);   // read-once
            f32x4 o;
            o[0] = (acc[4 * hf + 0] - mean) * rstd * g[0] + b[0] + xx[0];
            o[1] = (acc[4 * hf + 1] - mean) * rstd * g[1] + b[1] + xx[1];
            o[2] = (acc[4 * hf + 2] - mean) * rstd * g[2] + b[2] + xx[2];
            o[3] = (acc[4 * hf + 3] - mean) * rstd * g[3] + b[3] + xx[3];
            __builtin_nontemporal_store(o, orow + 2 * t + hf);        // write-once
        }
    }
}

extern "C" void kernel_launch(void* const* d_in, const int* in_sizes, int n_in,
                              void* d_out, int out_size, void* d_ws, size_t ws_size,
                              hipStream_t stream) {
    const float* x     = (const float*)d_in[0];
    const int*   ei    = (const int*)d_in[1];   // [2, E]
    const float* W     = (const float*)d_in[2];
    const float* bias  = (const float*)d_in[3];
    const float* gamma = (const float*)d_in[4];
    const float* beta  = (const float*)d_in[5];
    int N = in_sizes[0] / D;
    int E = in_sizes[1] / 2;
    int nb  = (N + 255) / 256;                   // 196 scan blocks (<=256)
    int nbE = (E + 255) / 256;                   // 3125
    int K   = (E + CHUNK - 1) >> CHSH;           // 25 chunks / copies
    int gemm_blocks = (N + 255) / 256;           // 196 (256 rows per 1024-thr block)

    char* ws = (char*)d_ws;
    size_t off = 0;
    unsigned short* hb  = (unsigned short*)(ws + off); off += (size_t)N * D * 2;       // 12.8 MB
    unsigned char* degc = (unsigned char*)(ws + off);  off += (size_t)K * N;           // 1.25 MB
    unsigned char* cntc = (unsigned char*)(ws + off);  off += (size_t)K * N;           // 1.25 MB
    float*    dis       = (float*)(ws + off);          off += (size_t)N * 4;
    int*      rowptr    = (int*)(ws + off);            off += (size_t)(N + 1) * 4;
    unsigned char* pre8 = (unsigned char*)(ws + off);  off += (size_t)K * N;           // 1.25 MB
    unsigned* partial   = (unsigned*)(ws + off);       off += 256 * 4;
    unsigned char* aux  = (unsigned char*)(ws + off);  off += (size_t)E;               // 0.8 MB
    off = (off + 1) & ~(size_t)1;
    unsigned short* srcs = (unsigned short*)(ws + off); off += (size_t)E * 2;          // 1.6 MB
    float*    out       = (float*)d_out;

    k_gemm_hist<<<2 * K + gemm_blocks, 1024, 0, stream>>>(x, W, bias, hb, N,
                                                          ei, E, N, degc, cntc, aux,
                                                          partial, K);
    k_scan<<<nb, 256, 0, stream>>>(degc, cntc, dis, rowptr, pre8, partial, N, E, K);
    k_fill<<<nbE, 256, 0, stream>>>(ei, E, N, rowptr, pre8, aux, srcs);
    k_agg<<<(N + 3) / 4, 256, 0, stream>>>(x, hb, dis, rowptr, srcs, gamma, beta, out, N);
}